// Round 1
// baseline (2617.432 us; speedup 1.0000x reference)
//
#include <hip/hip_runtime.h>
#include <math.h>

#define SEQ    2048
#define EMBED  1024
#define HEADS  16
#define HDIM   64
#define BATCH  4
#define ROWS   (BATCH * SEQ)    // 8192
#define BH     (BATCH * HEADS)  // 64

// ---------------------------------------------------------------------------
// Kernel 1: fused QKV projection.  C = x @ W^T + bias, stored as [b][h][s][d].
// grid (ROWS/128, EMBED/128, 3), block 256. 8x8 micro-tile, BK=16.
// ---------------------------------------------------------------------------
__global__ __launch_bounds__(256) void proj_kernel(
    const float* __restrict__ x,
    const float* __restrict__ Wq, const float* __restrict__ bq,
    const float* __restrict__ Wk, const float* __restrict__ bk,
    const float* __restrict__ Wv, const float* __restrict__ bv,
    float* __restrict__ Q, float* __restrict__ K, float* __restrict__ V)
{
    const float* W; const float* bias; float* Out;
    if (blockIdx.z == 0)      { W = Wq; bias = bq; Out = Q; }
    else if (blockIdx.z == 1) { W = Wk; bias = bk; Out = K; }
    else                      { W = Wv; bias = bv; Out = V; }

    // k-major LDS tiles; row length 132 floats keeps rows 16B-aligned and
    // write conflicts at 2-way (free per m136).
    __shared__ float Xs[16][132];
    __shared__ float Ws[16][132];

    const int t  = threadIdx.x;
    const int tx = t & 15;
    const int ty = t >> 4;
    const int r0 = blockIdx.x * 128;
    const int c0 = blockIdx.y * 128;

    const int ldrow = t >> 1;        // 0..127
    const int ldk   = (t & 1) * 8;   // 0 or 8

    float acc[8][8];
#pragma unroll
    for (int j = 0; j < 8; ++j)
#pragma unroll
        for (int i = 0; i < 8; ++i) acc[j][i] = 0.f;

    for (int kk = 0; kk < EMBED; kk += 16) {
        __syncthreads();
        float4 u0 = *(const float4*)&x[(size_t)(r0 + ldrow) * EMBED + kk + ldk];
        float4 u1 = *(const float4*)&x[(size_t)(r0 + ldrow) * EMBED + kk + ldk + 4];
        float4 w0 = *(const float4*)&W[(size_t)(c0 + ldrow) * EMBED + kk + ldk];
        float4 w1 = *(const float4*)&W[(size_t)(c0 + ldrow) * EMBED + kk + ldk + 4];
        Xs[ldk + 0][ldrow] = u0.x; Xs[ldk + 1][ldrow] = u0.y;
        Xs[ldk + 2][ldrow] = u0.z; Xs[ldk + 3][ldrow] = u0.w;
        Xs[ldk + 4][ldrow] = u1.x; Xs[ldk + 5][ldrow] = u1.y;
        Xs[ldk + 6][ldrow] = u1.z; Xs[ldk + 7][ldrow] = u1.w;
        Ws[ldk + 0][ldrow] = w0.x; Ws[ldk + 1][ldrow] = w0.y;
        Ws[ldk + 2][ldrow] = w0.z; Ws[ldk + 3][ldrow] = w0.w;
        Ws[ldk + 4][ldrow] = w1.x; Ws[ldk + 5][ldrow] = w1.y;
        Ws[ldk + 6][ldrow] = w1.z; Ws[ldk + 7][ldrow] = w1.w;
        __syncthreads();
#pragma unroll
        for (int k = 0; k < 16; ++k) {
            float4 a0 = *(const float4*)&Xs[k][ty * 4];
            float4 a1 = *(const float4*)&Xs[k][64 + ty * 4];
            float4 b0 = *(const float4*)&Ws[k][tx * 4];
            float4 b1 = *(const float4*)&Ws[k][64 + tx * 4];
            float ar[8] = {a0.x, a0.y, a0.z, a0.w, a1.x, a1.y, a1.z, a1.w};
            float br[8] = {b0.x, b0.y, b0.z, b0.w, b1.x, b1.y, b1.z, b1.w};
#pragma unroll
            for (int j = 0; j < 8; ++j)
#pragma unroll
                for (int i = 0; i < 8; ++i)
                    acc[j][i] = fmaf(ar[j], br[i], acc[j][i]);
        }
    }

    // store with [b][h][s][d] layout transform + bias
#pragma unroll
    for (int j = 0; j < 8; ++j) {
        int r = r0 + ((j < 4) ? (ty * 4 + j) : (64 + ty * 4 + (j - 4)));
        int b = r >> 11;        // / SEQ
        int s = r & (SEQ - 1);
#pragma unroll
        for (int i = 0; i < 8; ++i) {
            int c  = c0 + ((i < 4) ? (tx * 4 + i) : (64 + tx * 4 + (i - 4)));
            int h  = c >> 6;
            int dd = c & 63;
            Out[((size_t)(b * HEADS + h) * SEQ + s) * HDIM + dd] = acc[j][i] + bias[c];
        }
    }
}

// ---------------------------------------------------------------------------
// Kernel 2: column stats.  linv[bh][k] = 1 / sum_q exp(S[q,k] / 10).
// grid (SEQ/64, BH), block 256. 64q x 64k S tiles, 4x4 micro.
// No max-subtraction needed: |S/10| <~ 5, exp stays well inside fp32 range.
// ---------------------------------------------------------------------------
__global__ __launch_bounds__(256) void stats_kernel(
    const float* __restrict__ Q, const float* __restrict__ K,
    float* __restrict__ linv)
{
    const int bh = blockIdx.y;
    const int k0 = blockIdx.x * 64;
    const int t  = threadIdx.x;
    const int tx = t & 15;
    const int ty = t >> 4;

    __shared__ float Ks[64][65];
    __shared__ float Qs[64][65];
    __shared__ float red[64][17];

    // load K tile once (coalesced: 16 rows x 64 floats contiguous per wave)
    {
        int r  = t >> 2;
        int d0 = (t & 3) * 16;
        const float* src = &K[((size_t)bh * SEQ + (k0 + r)) * HDIM + d0];
        float4 v0 = *(const float4*)(src);
        float4 v1 = *(const float4*)(src + 4);
        float4 v2 = *(const float4*)(src + 8);
        float4 v3 = *(const float4*)(src + 12);
        float vals[16] = {v0.x, v0.y, v0.z, v0.w, v1.x, v1.y, v1.z, v1.w,
                          v2.x, v2.y, v2.z, v2.w, v3.x, v3.y, v3.z, v3.w};
#pragma unroll
        for (int j = 0; j < 16; ++j) Ks[r][d0 + j] = vals[j];
    }

    float ssum[4] = {0.f, 0.f, 0.f, 0.f};

    for (int q0 = 0; q0 < SEQ; q0 += 64) {
        __syncthreads();
        {
            int r  = t >> 2;
            int d0 = (t & 3) * 16;
            const float* src = &Q[((size_t)bh * SEQ + (q0 + r)) * HDIM + d0];
            float4 v0 = *(const float4*)(src);
            float4 v1 = *(const float4*)(src + 4);
            float4 v2 = *(const float4*)(src + 8);
            float4 v3 = *(const float4*)(src + 12);
            float vals[16] = {v0.x, v0.y, v0.z, v0.w, v1.x, v1.y, v1.z, v1.w,
                              v2.x, v2.y, v2.z, v2.w, v3.x, v3.y, v3.z, v3.w};
#pragma unroll
            for (int j = 0; j < 16; ++j) Qs[r][d0 + j] = vals[j];
        }
        __syncthreads();

        float s[4][4] = {};
#pragma unroll 4
        for (int d = 0; d < HDIM; ++d) {
            float a[4], b[4];
#pragma unroll
            for (int j = 0; j < 4; ++j) a[j] = Qs[ty * 4 + j][d];
#pragma unroll
            for (int i = 0; i < 4; ++i) b[i] = Ks[tx * 4 + i][d];
#pragma unroll
            for (int j = 0; j < 4; ++j)
#pragma unroll
                for (int i = 0; i < 4; ++i)
                    s[j][i] = fmaf(a[j], b[i], s[j][i]);
        }
#pragma unroll
        for (int j = 0; j < 4; ++j)
#pragma unroll
            for (int i = 0; i < 4; ++i)
                ssum[i] += __expf(s[j][i] * 0.1f);
    }

    __syncthreads();
#pragma unroll
    for (int i = 0; i < 4; ++i) red[tx * 4 + i][ty] = ssum[i];
    __syncthreads();
    if (t < 64) {
        float tot = 0.f;
#pragma unroll
        for (int p = 0; p < 16; ++p) tot += red[t][p];
        linv[(size_t)bh * SEQ + k0 + t] = 1.0f / tot;
    }
}

// ---------------------------------------------------------------------------
// Kernel 3: out[q,d] = sum_k exp(S[q,k]/10) * linv[k] * V[k,d]
// grid (SEQ/64, BH), block 256. Recompute S per 64x64 chunk, stage P in LDS.
// ---------------------------------------------------------------------------
__global__ __launch_bounds__(256) void out_kernel(
    const float* __restrict__ Q, const float* __restrict__ K,
    const float* __restrict__ V, const float* __restrict__ linv,
    float* __restrict__ out)
{
    const int bh = blockIdx.y;
    const int b  = bh >> 4;      // / HEADS
    const int h  = bh & 15;
    const int q0 = blockIdx.x * 64;
    const int t  = threadIdx.x;
    const int tx = t & 15;
    const int ty = t >> 4;

    __shared__ float Qs[64][65];
    __shared__ float Ks[64][65];
    __shared__ float Vs[64][65];
    __shared__ float Ss[64][65];

    {
        int r  = t >> 2;
        int d0 = (t & 3) * 16;
        const float* src = &Q[((size_t)bh * SEQ + (q0 + r)) * HDIM + d0];
        float4 v0 = *(const float4*)(src);
        float4 v1 = *(const float4*)(src + 4);
        float4 v2 = *(const float4*)(src + 8);
        float4 v3 = *(const float4*)(src + 12);
        float vals[16] = {v0.x, v0.y, v0.z, v0.w, v1.x, v1.y, v1.z, v1.w,
                          v2.x, v2.y, v2.z, v2.w, v3.x, v3.y, v3.z, v3.w};
#pragma unroll
        for (int j = 0; j < 16; ++j) Qs[r][d0 + j] = vals[j];
    }

    float acc[4][4] = {};

    for (int k0 = 0; k0 < SEQ; k0 += 64) {
        __syncthreads();
        {
            int r  = t >> 2;
            int d0 = (t & 3) * 16;
            const float* srck = &K[((size_t)bh * SEQ + (k0 + r)) * HDIM + d0];
            const float* srcv = &V[((size_t)bh * SEQ + (k0 + r)) * HDIM + d0];
            float4 a0 = *(const float4*)(srck);
            float4 a1 = *(const float4*)(srck + 4);
            float4 a2 = *(const float4*)(srck + 8);
            float4 a3 = *(const float4*)(srck + 12);
            float ka[16] = {a0.x, a0.y, a0.z, a0.w, a1.x, a1.y, a1.z, a1.w,
                            a2.x, a2.y, a2.z, a2.w, a3.x, a3.y, a3.z, a3.w};
            float4 c0 = *(const float4*)(srcv);
            float4 c1 = *(const float4*)(srcv + 4);
            float4 c2 = *(const float4*)(srcv + 8);
            float4 c3 = *(const float4*)(srcv + 12);
            float va[16] = {c0.x, c0.y, c0.z, c0.w, c1.x, c1.y, c1.z, c1.w,
                            c2.x, c2.y, c2.z, c2.w, c3.x, c3.y, c3.z, c3.w};
#pragma unroll
            for (int j = 0; j < 16; ++j) Ks[r][d0 + j] = ka[j];
#pragma unroll
            for (int j = 0; j < 16; ++j) Vs[r][d0 + j] = va[j];
        }
        __syncthreads();

        // S chunk: rows q = ty*4.., cols k = tx*4..
        float s[4][4] = {};
#pragma unroll 4
        for (int d = 0; d < HDIM; ++d) {
            float a[4], bb[4];
#pragma unroll
            for (int j = 0; j < 4; ++j) a[j] = Qs[ty * 4 + j][d];
#pragma unroll
            for (int i = 0; i < 4; ++i) bb[i] = Ks[tx * 4 + i][d];
#pragma unroll
            for (int j = 0; j < 4; ++j)
#pragma unroll
                for (int i = 0; i < 4; ++i)
                    s[j][i] = fmaf(a[j], bb[i], s[j][i]);
        }
        float li[4];
#pragma unroll
        for (int i = 0; i < 4; ++i) li[i] = linv[(size_t)bh * SEQ + k0 + tx * 4 + i];
#pragma unroll
        for (int j = 0; j < 4; ++j)
#pragma unroll
            for (int i = 0; i < 4; ++i)
                Ss[ty * 4 + j][tx * 4 + i] = __expf(s[j][i] * 0.1f) * li[i];
        __syncthreads();

        // PV: rows q = ty*4.., cols d = tx*4..
#pragma unroll 4
        for (int k = 0; k < 64; ++k) {
            float a[4], bb[4];
#pragma unroll
            for (int j = 0; j < 4; ++j) a[j] = Ss[ty * 4 + j][k];
#pragma unroll
            for (int i = 0; i < 4; ++i) bb[i] = Vs[k][tx * 4 + i];
#pragma unroll
            for (int j = 0; j < 4; ++j)
#pragma unroll
                for (int i = 0; i < 4; ++i)
                    acc[j][i] = fmaf(a[j], bb[i], acc[j][i]);
        }
    }

    // store: out[b][q][h*64+d]
#pragma unroll
    for (int j = 0; j < 4; ++j) {
        size_t row = (size_t)b * SEQ + q0 + ty * 4 + j;
#pragma unroll
        for (int i = 0; i < 4; ++i)
            out[row * EMBED + h * HDIM + tx * 4 + i] = acc[j][i];
    }
}

extern "C" void kernel_launch(void* const* d_in, const int* in_sizes, int n_in,
                              void* d_out, int out_size, void* d_ws, size_t ws_size,
                              hipStream_t stream) {
    const float* x  = (const float*)d_in[0];
    const float* Wq = (const float*)d_in[1];
    const float* bq = (const float*)d_in[2];
    const float* Wk = (const float*)d_in[3];
    const float* bk = (const float*)d_in[4];
    const float* Wv = (const float*)d_in[5];
    const float* bv = (const float*)d_in[6];
    float* out = (float*)d_out;

    float* ws   = (float*)d_ws;
    const size_t QKV = (size_t)BH * SEQ * HDIM;   // 8388608 floats
    float* Q    = ws;
    float* K    = ws + QKV;
    float* V    = ws + 2 * QKV;
    float* linv = ws + 3 * QKV;                   // 131072 floats
    // total ws use: ~97 MB

    proj_kernel<<<dim3(ROWS / 128, EMBED / 128, 3), 256, 0, stream>>>(
        x, Wq, bq, Wk, bk, Wv, bv, Q, K, V);
    stats_kernel<<<dim3(SEQ / 64, BH), 256, 0, stream>>>(Q, K, linv);
    out_kernel<<<dim3(SEQ / 64, BH), 256, 0, stream>>>(Q, K, V, linv, out);
}

// Round 2
// 340.110 us; speedup vs baseline: 7.6958x; 7.6958x over previous
//
#include <hip/hip_runtime.h>
#include <math.h>

#define SEQ    2048
#define EMBED  1024
#define HEADS  16
#define HDIM   64
#define BATCH  4
#define ROWS   (BATCH * SEQ)    // 8192
#define BH     (BATCH * HEADS)  // 64

typedef _Float16 f16;
typedef __attribute__((ext_vector_type(8))) _Float16 f16x8;
typedef __attribute__((ext_vector_type(4))) _Float16 f16x4;
typedef __attribute__((ext_vector_type(4))) float    f32x4;

// async global->LDS copy, 16B per lane. LDS dest = uniform base + lane*16.
__device__ __forceinline__ void async16(void* l, const void* g) {
    __builtin_amdgcn_global_load_lds(
        (__attribute__((address_space(1))) void*)(uintptr_t)g,
        (__attribute__((address_space(3))) void*)(uint32_t)(uintptr_t)l,
        16, 0, 0);
}
// 4B per lane (for small fp32 vectors like linv tiles)
__device__ __forceinline__ void async4(void* l, const void* g) {
    __builtin_amdgcn_global_load_lds(
        (__attribute__((address_space(1))) void*)(uintptr_t)g,
        (__attribute__((address_space(3))) void*)(uint32_t)(uintptr_t)l,
        4, 0, 0);
}

__device__ __forceinline__ f32x4 mfma16(f16x8 a, f16x8 b, f32x4 c) {
    return __builtin_amdgcn_mfma_f32_16x16x32_f16(a, b, c, 0, 0, 0);
}

// ---------------------------------------------------------------------------
// Kernel 0: fp32 -> fp16 convert. x -> xh [8192][1024]; Wq/Wk/Wv -> Wh
// concatenated [3072][1024]. Memory-bound, ~15us.
// ---------------------------------------------------------------------------
#define NX4 (ROWS * EMBED / 4)          // 2097152
#define NW4 (EMBED * EMBED / 4)         // 262144
__global__ __launch_bounds__(256) void cvt_kernel(
    const float* __restrict__ x,
    const float* __restrict__ Wq, const float* __restrict__ Wk,
    const float* __restrict__ Wv,
    f16* __restrict__ xh, f16* __restrict__ Wh)
{
    int i = blockIdx.x * 256 + threadIdx.x;
    const float4* src; f16* dst; int j;
    if (i < NX4)              { src = (const float4*)x;  dst = xh;                j = i; }
    else if (i < NX4 + NW4)   { src = (const float4*)Wq; dst = Wh;                j = i - NX4; }
    else if (i < NX4 + 2*NW4) { src = (const float4*)Wk; dst = Wh + EMBED*EMBED;  j = i - NX4 - NW4; }
    else                      { src = (const float4*)Wv; dst = Wh + 2*EMBED*EMBED;j = i - NX4 - 2*NW4; }
    float4 v = src[j];
    f16x4 h;
    h[0] = (f16)v.x; h[1] = (f16)v.y; h[2] = (f16)v.z; h[3] = (f16)v.w;
    *(f16x4*)(dst + (size_t)j * 4) = h;
}

// ---------------------------------------------------------------------------
// Kernel 1: fused QKV projection GEMM (f16 MFMA, m97 structure).
// C[8192][3072] = xh @ Wh^T + bias. 128x128 tile, BK=32, global_load_lds w=16.
// Epilogue: Q,K -> [bh][s][d] fp16; V -> transposed Vt [bh][d][s] fp16.
// ---------------------------------------------------------------------------
__global__ __launch_bounds__(256) void proj_kernel(
    const f16* __restrict__ A,   // [8192][1024]
    const f16* __restrict__ W,   // [3072][1024]
    const float* __restrict__ bq, const float* __restrict__ bk,
    const float* __restrict__ bv,
    f16* __restrict__ Qh, f16* __restrict__ Kh, f16* __restrict__ Vt)
{
    __shared__ f16 As[128 * 32];   // [row][32k], rows 64B, unpadded (glds layout)
    __shared__ f16 Bs[128 * 32];

    const int t = threadIdx.x, wv = t >> 6, lane = t & 63;
    const int lm = lane & 15, quad = lane >> 4;
    const int r0 = blockIdx.x * 128, c0 = blockIdx.y * 128;
    const int wm = wv & 1, wn = wv >> 1;

    // staging: each wave stages 32 rows of A and B (2 x 16-row instructions)
    const int srow = wv * 32 + (lane >> 2);
    const int sch  = (lane & 3) * 8;     // f16 units (16B chunks)
    const f16* gA = A + (size_t)(r0 + srow) * EMBED + sch;
    const f16* gB = W + (size_t)(c0 + srow) * EMBED + sch;
    f16* lA = As + wv * 1024;
    f16* lB = Bs + wv * 1024;

    f32x4 acc[4][4];
#pragma unroll
    for (int i = 0; i < 4; ++i)
#pragma unroll
        for (int j = 0; j < 4; ++j) acc[i][j] = (f32x4){0.f, 0.f, 0.f, 0.f};

    for (int kk = 0; kk < EMBED; kk += 32) {
        __syncthreads();
        async16(lA,        gA + kk);
        async16(lA + 512,  gA + 16 * EMBED + kk);
        async16(lB,        gB + kk);
        async16(lB + 512,  gB + 16 * EMBED + kk);
        __syncthreads();

        f16x8 af[4], bf[4];
#pragma unroll
        for (int i = 0; i < 4; ++i)
            af[i] = *(const f16x8*)&As[(wm * 64 + i * 16 + lm) * 32 + quad * 8];
#pragma unroll
        for (int i = 0; i < 4; ++i)
            bf[i] = *(const f16x8*)&Bs[(wn * 64 + i * 16 + lm) * 32 + quad * 8];
#pragma unroll
        for (int mi = 0; mi < 4; ++mi)
#pragma unroll
            for (int ni = 0; ni < 4; ++ni)
                acc[mi][ni] = mfma16(af[mi], bf[ni], acc[mi][ni]);
    }

    // epilogue: bias + cvt + scatter into attention layouts
    const int z = c0 >> 10;              // 0=Q 1=K 2=V (128 | 1024 so no straddle)
    const float* bias = (z == 0) ? bq : (z == 1) ? bk : bv;
#pragma unroll
    for (int ni = 0; ni < 4; ++ni) {
        int col = c0 + wn * 64 + ni * 16 + lm;
        int cz  = col & 1023;
        float bb = bias[cz];
        int h = cz >> 6, d = cz & 63;
#pragma unroll
        for (int mi = 0; mi < 4; ++mi) {
            int rbase = r0 + wm * 64 + mi * 16 + quad * 4;
            int b = rbase >> 11, s = rbase & 2047;   // 4 rows stay in same b
            if (z < 2) {
                f16* O = (z == 0) ? Qh : Kh;
                size_t base = ((size_t)(b * HEADS + h) * SEQ + s) * HDIM + d;
#pragma unroll
                for (int r = 0; r < 4; ++r)
                    O[base + (size_t)r * HDIM] = (f16)(acc[mi][ni][r] + bb);
            } else {
                f16x4 pk;
#pragma unroll
                for (int r = 0; r < 4; ++r) pk[r] = (f16)(acc[mi][ni][r] + bb);
                *(f16x4*)&Vt[((size_t)(b * HEADS + h) * HDIM + d) * SEQ + s] = pk;
            }
        }
    }
}

// ---------------------------------------------------------------------------
// Kernel 2: column stats. linv[bh][k] = 1 / sum_q exp(S[q,k]/10).
// grid (16, 64): block owns 128 k-cols; K-frags pinned in regs; q swept in
// 64-row LDS tiles. S via f16 MFMA (D[m=q][n=k]); colsum reduced over quads.
// ---------------------------------------------------------------------------
__global__ __launch_bounds__(256) void stats_kernel(
    const f16* __restrict__ Qh, const f16* __restrict__ Kh,
    float* __restrict__ linv)
{
    __shared__ f16 Ks[128 * 64];   // [kcol][d] rows 128B
    __shared__ f16 Qs[64 * 64];    // [q][d]

    const int t = threadIdx.x, wv = t >> 6, lane = t & 63;
    const int lm = lane & 15, quad = lane >> 4;
    const int bh = blockIdx.y, k0 = blockIdx.x * 128;
    const int grow = lane >> 3, gch = (lane & 7) * 8;
    const size_t base = (size_t)bh * SEQ * HDIM;

#pragma unroll
    for (int i = 0; i < 4; ++i) {
        int g = wv * 4 + i;
        async16(Ks + g * 512, Kh + base + (size_t)(k0 + g * 8 + grow) * HDIM + gch);
    }
    __syncthreads();

    f16x8 kf[2][2];   // [coltile][dstep] -- stays in registers all sweep
#pragma unroll
    for (int ct = 0; ct < 2; ++ct)
#pragma unroll
        for (int ds = 0; ds < 2; ++ds)
            kf[ct][ds] = *(const f16x8*)&Ks[(wv * 32 + ct * 16 + lm) * 64 + ds * 32 + quad * 8];

    float cs0 = 0.f, cs1 = 0.f;
    for (int q0 = 0; q0 < SEQ; q0 += 64) {
        __syncthreads();
#pragma unroll
        for (int i = 0; i < 2; ++i) {
            int g = wv * 2 + i;
            async16(Qs + g * 512, Qh + base + (size_t)(q0 + g * 8 + grow) * HDIM + gch);
        }
        __syncthreads();
#pragma unroll
        for (int qt = 0; qt < 4; ++qt) {
            f16x8 a0 = *(const f16x8*)&Qs[(qt * 16 + lm) * 64 + quad * 8];
            f16x8 a1 = *(const f16x8*)&Qs[(qt * 16 + lm) * 64 + 32 + quad * 8];
            f32x4 c0v = (f32x4){0.f, 0.f, 0.f, 0.f};
            f32x4 c1v = (f32x4){0.f, 0.f, 0.f, 0.f};
            c0v = mfma16(a0, kf[0][0], c0v); c0v = mfma16(a1, kf[0][1], c0v);
            c1v = mfma16(a0, kf[1][0], c1v); c1v = mfma16(a1, kf[1][1], c1v);
#pragma unroll
            for (int r = 0; r < 4; ++r) {
                cs0 += __expf(c0v[r] * 0.1f);
                cs1 += __expf(c1v[r] * 0.1f);
            }
        }
    }
    // reduce the quad dimension (rows of the C tiles) across lanes
    cs0 += __shfl_xor(cs0, 16, 64); cs0 += __shfl_xor(cs0, 32, 64);
    cs1 += __shfl_xor(cs1, 16, 64); cs1 += __shfl_xor(cs1, 32, 64);
    if (quad == 0) {
        linv[(size_t)bh * SEQ + k0 + wv * 32 + lm]      = 1.0f / cs0;
        linv[(size_t)bh * SEQ + k0 + wv * 32 + 16 + lm] = 1.0f / cs1;
    }
}

// ---------------------------------------------------------------------------
// Kernel 3: out[q,d] = (1/1024) * sum_k P''[q,k] * V[k,d],
//           P'' = exp(S/10) * linv[k] * 1024  (fp16, range [6e-3, 20]).
// grid (16, 64): block = 128 q rows (32/wave), sweep k in 64-tiles.
// Computes S^T = K.Q^T so C-layout rows = k -> pack 4 consecutive-k P vals
// into ds_write_b64 into padded (72 f16/row) per-wave P region; then P @ Vt.
// ---------------------------------------------------------------------------
__global__ __launch_bounds__(256) void out_kernel(
    const f16* __restrict__ Qh, const f16* __restrict__ Kh,
    const f16* __restrict__ Vt, const float* __restrict__ linv,
    float* __restrict__ out)
{
    __shared__ f16 Ps[4 * 32 * 72];   // Q staging (unpadded) then P (padded 72)
    __shared__ f16 Ks[64 * 64];       // [k][d]
    __shared__ f16 Vs[64 * 64];       // [d][s-chunk] (from Vt)
    __shared__ float Ls[64];

    const int t = threadIdx.x, wv = t >> 6, lane = t & 63;
    const int lm = lane & 15, quad = lane >> 4;
    const int bh = blockIdx.y, q0 = blockIdx.x * 128;
    const int b = bh >> 4, h = bh & 15;
    const int grow = lane >> 3, gch = (lane & 7) * 8;
    const size_t base = (size_t)bh * SEQ * HDIM;   // same stride for Qh/Kh/Vt

    // stage Q[128][64] (unpadded rows of 64); each wave stages its own 32 rows
#pragma unroll
    for (int i = 0; i < 4; ++i) {
        int g = wv * 4 + i;
        async16(Ps + g * 512, Qh + base + (size_t)(q0 + g * 8 + grow) * HDIM + gch);
    }
    __syncthreads();
    f16x8 qa[2][2];   // Q fragments, pinned in regs (also reused as B-operand)
#pragma unroll
    for (int qs = 0; qs < 2; ++qs)
#pragma unroll
        for (int ds = 0; ds < 2; ++ds)
            qa[qs][ds] = *(const f16x8*)&Ps[(wv * 32 + qs * 16 + lm) * 64 + ds * 32 + quad * 8];

    f32x4 oacc[2][4];
#pragma unroll
    for (int i = 0; i < 2; ++i)
#pragma unroll
        for (int j = 0; j < 4; ++j) oacc[i][j] = (f32x4){0.f, 0.f, 0.f, 0.f};

    f16* Pw = Ps + wv * (32 * 72);    // per-wave padded P region

    for (int k0 = 0; k0 < SEQ; k0 += 64) {
        __syncthreads();   // drains everyone's LDS reads (incl. iter-0 qa reads)
#pragma unroll
        for (int i = 0; i < 2; ++i) {
            int g = wv * 2 + i;
            async16(Ks + g * 512, Kh + base + (size_t)(k0 + g * 8 + grow) * HDIM + gch);
            async16(Vs + g * 512, Vt + base + (size_t)(g * 8 + grow) * SEQ + k0 + gch);
        }
        if (wv == 0) async4(Ls, linv + (size_t)bh * SEQ + k0 + lane);
        __syncthreads();

        // S^T tiles: D[m=k][n=q] = K . Q^T; exp + linv + pack to P[q][k] (padded)
#pragma unroll
        for (int ct = 0; ct < 4; ++ct) {
            f16x8 kf0 = *(const f16x8*)&Ks[(ct * 16 + lm) * 64 + quad * 8];
            f16x8 kf1 = *(const f16x8*)&Ks[(ct * 16 + lm) * 64 + 32 + quad * 8];
            float li[4];
#pragma unroll
            for (int r = 0; r < 4; ++r) li[r] = Ls[ct * 16 + quad * 4 + r] * 1024.0f;
#pragma unroll
            for (int qs = 0; qs < 2; ++qs) {
                f32x4 s4 = (f32x4){0.f, 0.f, 0.f, 0.f};
                s4 = mfma16(kf0, qa[qs][0], s4);
                s4 = mfma16(kf1, qa[qs][1], s4);
                f16x4 pk;
#pragma unroll
                for (int r = 0; r < 4; ++r)
                    pk[r] = (f16)(__expf(s4[r] * 0.1f) * li[r]);
                // row q = qs*16+lm, cols k = ct*16+quad*4..+3 (contiguous, 8B store)
                *(f16x4*)&Pw[(qs * 16 + lm) * 72 + ct * 16 + quad * 4] = pk;
            }
        }
        // PV: D[m=q][n=d] = P @ Vt  (same-wave DS ordering makes P visible)
#pragma unroll
        for (int ks = 0; ks < 2; ++ks) {
            f16x8 pa0 = *(const f16x8*)&Pw[(lm) * 72 + ks * 32 + quad * 8];
            f16x8 pa1 = *(const f16x8*)&Pw[(16 + lm) * 72 + ks * 32 + quad * 8];
#pragma unroll
            for (int dt = 0; dt < 4; ++dt) {
                f16x8 vb = *(const f16x8*)&Vs[(dt * 16 + lm) * 64 + ks * 32 + quad * 8];
                oacc[0][dt] = mfma16(pa0, vb, oacc[0][dt]);
                oacc[1][dt] = mfma16(pa1, vb, oacc[1][dt]);
            }
        }
    }

    const float inv1024 = 1.0f / 1024.0f;
#pragma unroll
    for (int qt = 0; qt < 2; ++qt)
#pragma unroll
        for (int dt = 0; dt < 4; ++dt) {
            int col = h * HDIM + dt * 16 + lm;
#pragma unroll
            for (int r = 0; r < 4; ++r) {
                int s = q0 + wv * 32 + qt * 16 + quad * 4 + r;
                out[((size_t)b * SEQ + s) * EMBED + col] = oacc[qt][dt][r] * inv1024;
            }
        }
}

extern "C" void kernel_launch(void* const* d_in, const int* in_sizes, int n_in,
                              void* d_out, int out_size, void* d_ws, size_t ws_size,
                              hipStream_t stream) {
    const float* x  = (const float*)d_in[0];
    const float* Wq = (const float*)d_in[1];
    const float* bq = (const float*)d_in[2];
    const float* Wk = (const float*)d_in[3];
    const float* bk = (const float*)d_in[4];
    const float* Wv = (const float*)d_in[5];
    const float* bv = (const float*)d_in[6];
    float* out = (float*)d_out;

    f16* xh = (f16*)d_ws;                          // 8388608
    f16* Wh = xh + (size_t)ROWS * EMBED;           // 3145728
    f16* Qh = Wh + (size_t)3 * EMBED * EMBED;      // 8388608
    f16* Kh = Qh + (size_t)BH * SEQ * HDIM;        // 8388608
    f16* Vt = Kh + (size_t)BH * SEQ * HDIM;        // 8388608
    float* linv = (float*)(Vt + (size_t)BH * SEQ * HDIM);   // 131072 fp32
    // total ws use ~70.5 MB

    cvt_kernel<<<(NX4 + 3 * NW4) / 256, 256, 0, stream>>>(x, Wq, Wk, Wv, xh, Wh);
    proj_kernel<<<dim3(ROWS / 128, 3 * EMBED / 128), 256, 0, stream>>>(
        xh, Wh, bq, bk, bv, Qh, Kh, Vt);
    stats_kernel<<<dim3(SEQ / 128, BH), 256, 0, stream>>>(Qh, Kh, linv);
    out_kernel<<<dim3(SEQ / 128, BH), 256, 0, stream>>>(Qh, Kh, Vt, linv, out);
}